// Round 6
// baseline (437.368 us; speedup 1.0000x reference)
//
#include <hip/hip_runtime.h>
#include <hip/hip_bf16.h>
#include <stdint.h>

#define GN 8192
#define GF 128
#define NEG_SLOPE 0.2f
#define BIGM 700.0f       // exp(-700) == 0.0f: masked entries vanish exactly
#define PST 132           // P-tile LDS row stride (shorts)

typedef __attribute__((ext_vector_type(8))) short bf16x8;
typedef __attribute__((ext_vector_type(4))) float f32x4;

__device__ __forceinline__ unsigned fkey(float f) {
    unsigned u = __float_as_uint(f);
    return (u & 0x80000000u) ? ~u : (u | 0x80000000u);
}
__device__ __forceinline__ float funkey(unsigned k) {
    unsigned b = (k & 0x80000000u) ? (k & 0x7FFFFFFFu) : ~k;
    return __uint_as_float(b);
}
__device__ __forceinline__ unsigned short bf16rne(float f) {
    unsigned u = __float_as_uint(f);
    return (unsigned short)((u + 0x7FFFu + ((u >> 16) & 1u)) >> 16);
}
// pack two fp32 -> two bf16 (round-half-up) in one v_perm
__device__ __forceinline__ unsigned packbf(float lo, float hi) {
    return __builtin_amdgcn_perm(__float_as_uint(hi) + 0x8000u,
                                 __float_as_uint(lo) + 0x8000u, 0x07060302u);
}

// K1: x' = x@W + b (fp32); writes XPT = x'^T as bf16 [GF][GN], s_src, s_dst.
__global__ __launch_bounds__(256) void gat_k1(
    const float* __restrict__ x, const float* __restrict__ w,
    const float* __restrict__ bias, const float* __restrict__ phi,
    unsigned short* __restrict__ xpt, float* __restrict__ s_src,
    float* __restrict__ s_dst)
{
    __shared__ float Xl[16][132];
    __shared__ float Wl[32][132];
    __shared__ unsigned short TR[128][24];
    const int tid = threadIdx.x;
    const int i0 = blockIdx.x * 16;

    #pragma unroll
    for (int q = 0; q < 2; q++) {                 // stage 16x128 x tile
        int flat = (q * 256 + tid) * 4;
        int r = flat >> 7, c = flat & 127;
        *(float4*)&Xl[r][c] = *(const float4*)&x[(size_t)(i0 + r) * GF + c];
    }

    const int rid = tid >> 5;          // 0..7 -> rows 2rid, 2rid+1
    const int c0  = (tid & 31) * 4;    // 4 consecutive features

    float acc[2][4] = {};
    for (int kc = 0; kc < 4; kc++) {   // W staged in 32-row chunks
        __syncthreads();
        #pragma unroll
        for (int q = 0; q < 4; q++) {
            int flat = (q * 256 + tid) * 4;
            int kk = flat >> 7, c = flat & 127;
            *(float4*)&Wl[kk][c] = *(const float4*)&w[(size_t)(kc * 32 + kk) * GF + c];
        }
        __syncthreads();
        #pragma unroll
        for (int k = 0; k < 32; k++) {
            float4 wv = *(const float4*)&Wl[k][c0];
            #pragma unroll
            for (int m = 0; m < 2; m++) {
                float xv = Xl[rid * 2 + m][kc * 32 + k];
                acc[m][0] = fmaf(xv, wv.x, acc[m][0]);
                acc[m][1] = fmaf(xv, wv.y, acc[m][1]);
                acc[m][2] = fmaf(xv, wv.z, acc[m][2]);
                acc[m][3] = fmaf(xv, wv.w, acc[m][3]);
            }
        }
    }

    float b4[4], p1[4], p2[4];
    #pragma unroll
    for (int q = 0; q < 4; q++) {
        b4[q] = bias[c0 + q];
        p1[q] = phi[c0 + q];
        p2[q] = phi[GF + c0 + q];
    }
    #pragma unroll
    for (int m = 0; m < 2; m++) {
        float ps = 0.f, pd = 0.f;
        #pragma unroll
        for (int q = 0; q < 4; q++) {
            float v = acc[m][q] + b4[q];
            ps = fmaf(v, p1[q], ps);
            pd = fmaf(v, p2[q], pd);
            TR[c0 + q][rid * 2 + m] = bf16rne(v);   // LDS transpose staging
        }
        #pragma unroll
        for (int s = 16; s >= 1; s >>= 1) {
            ps += __shfl_xor(ps, s, 64);
            pd += __shfl_xor(pd, s, 64);
        }
        if ((tid & 31) == 0) {
            s_src[i0 + rid * 2 + m] = ps;
            s_dst[i0 + rid * 2 + m] = pd;
        }
    }
    __syncthreads();
    {   // coalesced transposed store
        const int f = tid >> 1, part = (tid & 1) * 8;
        uint2 lo = *(const uint2*)&TR[f][part];
        uint2 hi = *(const uint2*)&TR[f][part + 4];
        uint4 o; o.x = lo.x; o.y = lo.y; o.z = hi.x; o.w = hi.y;
        *(uint4*)&xpt[(size_t)f * GN + i0 + part] = o;
    }
}

// K1b: D = max(s_dst). 8 blocks -> only 8 same-address atomics.
__global__ __launch_bounds__(256) void gat_k1b(
    const float* __restrict__ s_dst, unsigned* __restrict__ Dkey)
{
    __shared__ float sm[4];
    const int tid = threadIdx.x;
    const int idx = (blockIdx.x * 256 + tid) * 4;
    float4 v = *(const float4*)&s_dst[idx];
    float m = fmaxf(fmaxf(v.x, v.y), fmaxf(v.z, v.w));
    #pragma unroll
    for (int s = 32; s >= 1; s >>= 1) m = fmaxf(m, __shfl_xor(m, s, 64));
    if ((tid & 63) == 0) sm[tid >> 6] = m;
    __syncthreads();
    if (tid == 0) {
        m = fmaxf(fmaxf(sm[0], sm[1]), fmaxf(sm[2], sm[3]));
        atomicMax(Dkey, fkey(m));
    }
}

// K2: flash GAT. Block = 16 rows, 4 waves; wave w owns 64-col chunks (4t+w).
// amdgpu_waves_per_eu(2,2) pins occupancy at 2 waves/EU so the allocator gets
// a 256-VGPR budget: B-frags (64 VGPRs) + depth-2 adj prefetch (32) stay live
// and in flight instead of being serialized for a 6-wave occupancy target.
// Issue order per iter: B(t) [16 loads] -> P-compute (VALU shadow for B) ->
// apf(t+2) [4 loads, youngest so MFMA's vmcnt leaves them in flight] -> MFMA.
__global__ __attribute__((amdgpu_waves_per_eu(2, 2)))
__launch_bounds__(256) void gat_k2(
    const float* __restrict__ adj, const unsigned short* __restrict__ xpt,
    const float* __restrict__ s_src, const float* __restrict__ s_dst,
    const unsigned* __restrict__ Dkey, float* __restrict__ out)
{
    __shared__ float smem[8448];               // K-loop: s_dst copy; epilogue: Ol[4][16][132]
    __shared__ unsigned short Pl[4][16 * PST]; // per-wave private P tiles
    __shared__ float Zl[4][16];

    const int tid  = threadIdx.x;
    const int wave = tid >> 6, lane = tid & 63;
    const int m16  = lane & 15, q4 = lane >> 4;
    const int i0   = blockIdx.x * 16;

    #pragma unroll
    for (int s = 0; s < 8; s++) {    // stage all of s_dst into LDS (32 KB)
        const int idx = (s * 256 + tid) * 4;
        *(float4*)&smem[idx] = *(const float4*)&s_dst[idx];
    }

    const float D = funkey(*Dkey);
    float si4[4], mneg4[4];          // per-lane softmax state for rows i0+4h+q4
    #pragma unroll
    for (int h = 0; h < 4; h++) {
        const float s = s_src[i0 + h * 4 + q4];
        si4[h] = s;
        const float t0 = s + D;
        mneg4[h] = -fmaxf(t0, NEG_SLOPE * t0);   // -Mi >= -(row max) bound
    }

    unsigned short* Plw = (unsigned short*)Pl[wave];
    const float* adjb = adj + (size_t)(i0 + q4) * GN + m16 * 4;

    f32x4 acc[8];
    #pragma unroll
    for (int fg = 0; fg < 8; fg++) acc[fg] = (f32x4){0.f, 0.f, 0.f, 0.f};
    float z4[4] = {0.f, 0.f, 0.f, 0.f};

    __syncthreads();                 // s_dst LDS visible to all waves

    float4 apfA[4], apfB[4];         // depth-2 ping-pong adj prefetch
    #pragma unroll
    for (int h = 0; h < 4; h++) {
        apfA[h] = *(const float4*)(adjb + (size_t)h * 4 * GN + (0 * 4 + wave) * 64);
        apfB[h] = *(const float4*)(adjb + (size_t)h * 4 * GN + (1 * 4 + wave) * 64);
    }

    auto body = [&](int t, float4* apf) {
        const int cbase = (t * 4 + wave) * 64;

        // ---- B-frags for this chunk: issued FIRST (P-compute is their shadow)
        bf16x8 B0[8], B1[8];
        const unsigned short* xb = xpt + (size_t)m16 * GN + cbase + q4 * 8;
        #pragma unroll
        for (int fg = 0; fg < 8; fg++) {
            B0[fg] = *(const bf16x8*)(xb + (size_t)(fg * 16) * GN);
            B1[fg] = *(const bf16x8*)(xb + (size_t)(fg * 16) * GN + 32);
        }

        // ---- P tile from prefetched adj (regs) + LDS s_dst
        const float4 d4 = *(const float4*)&smem[cbase + m16 * 4];
        #pragma unroll
        for (int h = 0; h < 4; h++) {            // row i0+4h+q4, cols m16*4..+3
            const float4 a = apf[h];
            const float si = si4[h], mneg = mneg4[h];
            const int irh = i0 + h * 4 + q4;
            float p[4];
            #pragma unroll
            for (int q = 0; q < 4; q++) {
                const float tt = si + (&d4.x)[q];
                const float lr = fmaxf(tt, NEG_SLOPE * tt);
                float zz = fmaf((&a.x)[q], BIGM, lr + (mneg - BIGM));
                if (cbase + m16 * 4 + q == irh) zz = lr + mneg;  // self-loop
                p[q] = __expf(zz);
            }
            z4[h] += (p[0] + p[1]) + (p[2] + p[3]);
            *(uint2*)&Plw[(h * 4 + q4) * PST + m16 * 4] =
                make_uint2(packbf(p[0], p[1]), packbf(p[2], p[3]));
        }

        // A-frags from own-wave LDS tile (lgkmcnt only, no barrier)
        const bf16x8 af0 = *(const bf16x8*)&Plw[m16 * PST + q4 * 8];
        const bf16x8 af1 = *(const bf16x8*)&Plw[m16 * PST + 32 + q4 * 8];

        // ---- adj prefetch for chunk t+2 (youngest in vmcnt queue: MFMA's
        // wait for B leaves these in flight ~1.5 iterations)
        if (t < 30) {
            const int nb = (t * 4 + 8 + wave) * 64;
            #pragma unroll
            for (int h = 0; h < 4; h++)
                apf[h] = *(const float4*)(adjb + (size_t)h * 4 * GN + nb);
        }

        // ---- MFMA
        #pragma unroll
        for (int fg = 0; fg < 8; fg++)
            acc[fg] = __builtin_amdgcn_mfma_f32_16x16x32_bf16(af0, B0[fg], acc[fg], 0, 0, 0);
        #pragma unroll
        for (int fg = 0; fg < 8; fg++)
            acc[fg] = __builtin_amdgcn_mfma_f32_16x16x32_bf16(af1, B1[fg], acc[fg], 0, 0, 0);
    };

    #pragma unroll 1
    for (int t = 0; t < 32; t += 2) {
        body(t, apfA);
        body(t + 1, apfB);
    }

    // Z: reduce z4 across the 16 m16-lanes (same q4 => same row set)
    #pragma unroll
    for (int s = 1; s <= 8; s <<= 1)
        #pragma unroll
        for (int h = 0; h < 4; h++) z4[h] += __shfl_xor(z4[h], s, 64);

    __syncthreads();                 // all waves done reading s_dst LDS
    // epilogue: reuse smem as Ol[4][16][132]; C layout col=lane&15, row=q4*4+v
    #pragma unroll
    for (int fg = 0; fg < 8; fg++)
        #pragma unroll
        for (int v = 0; v < 4; v++)
            smem[(wave * 16 + q4 * 4 + v) * 132 + fg * 16 + m16] = acc[fg][v];

    if (m16 == 0) {
        #pragma unroll
        for (int h = 0; h < 4; h++) Zl[wave][h * 4 + q4] = z4[h];
    }
    __syncthreads();

    {   // cross-wave reduce + normalize: thread -> row tid>>4, 8 cols
        const int r = tid >> 4, c = (tid & 15) * 8;
        const float invz = 1.0f / (Zl[0][r] + Zl[1][r] + Zl[2][r] + Zl[3][r]);
        f32x4 s0 = {0.f, 0.f, 0.f, 0.f}, s1 = {0.f, 0.f, 0.f, 0.f};
        #pragma unroll
        for (int wv = 0; wv < 4; wv++) {
            s0 += *(const f32x4*)&smem[(wv * 16 + r) * 132 + c];
            s1 += *(const f32x4*)&smem[(wv * 16 + r) * 132 + c + 4];
        }
        s0 *= invz; s1 *= invz;
        *(f32x4*)&out[(size_t)(i0 + r) * GF + c]     = s0;
        *(f32x4*)&out[(size_t)(i0 + r) * GF + c + 4] = s1;
    }
}

extern "C" void kernel_launch(void* const* d_in, const int* in_sizes, int n_in,
                              void* d_out, int out_size, void* d_ws, size_t ws_size,
                              hipStream_t stream)
{
    (void)in_sizes; (void)n_in; (void)out_size; (void)ws_size;
    const float* adj  = (const float*)d_in[0];
    const float* x    = (const float*)d_in[1];
    const float* w    = (const float*)d_in[2];
    const float* bias = (const float*)d_in[3];
    const float* phi  = (const float*)d_in[4];
    float* out = (float*)d_out;

    char* ws = (char*)d_ws;
    unsigned short* xpt = (unsigned short*)ws;             // 2 MB bf16 x'^T [GF][GN]
    float* s_src = (float*)(ws + (size_t)GF * GN * 2);     // 32 KB
    float* s_dst = s_src + GN;                             // 32 KB
    unsigned* Dkey = (unsigned*)(s_dst + GN);              // 4 B

    hipMemsetAsync(Dkey, 0, sizeof(unsigned), stream);
    gat_k1 <<<GN / 16, 256, 0, stream>>>(x, w, bias, phi, xpt, s_src, s_dst);
    gat_k1b<<<8, 256, 0, stream>>>(s_dst, Dkey);
    gat_k2 <<<GN / 16, 256, 0, stream>>>(adj, xpt, s_src, s_dst, Dkey, out);
}